// Round 1
// baseline (1093.564 us; speedup 1.0000x reference)
//
#include <hip/hip_runtime.h>

#define B_    1024
#define L_    200
#define M_    (B_ * L_)     // 204800
#define E_    128
#define C_    384
#define K_    384
#define OUT_  10000
#define NT_   (M_ / 32)     // 6400 tiles of 32 rows
#define FCG_  768           // persistent fc grid: 3 blocks/CU x 256 CU

typedef __attribute__((ext_vector_type(8))) short bf16x8;
typedef __attribute__((ext_vector_type(4))) float f32x4;
typedef unsigned short u16;

__device__ __forceinline__ u16 f2bf(float f) {
    union { float f; unsigned u; } v; v.f = f;
    unsigned u = v.u;
    unsigned r = (u + 0x7fffu + ((u >> 16) & 1u)) >> 16;  // RNE
    return (u16)r;
}
__device__ __forceinline__ float bf2f(u16 s) {
    union { unsigned u; float f; } v; v.u = ((unsigned)s) << 16; return v.f;
}

// LDS-visibility barrier WITHOUT vmcnt drain: keeps next-tile gathers in flight
// across the barrier (raw s_barrier; __syncthreads would drain vmcnt(0)).
#define WG_BARRIER() asm volatile("s_waitcnt lgkmcnt(0)\n\ts_barrier" ::: "memory")

// ---------------- convert f32 -> bf16 (vectorized) ----------------
__global__ void cvt_bf16_kernel(const float4* __restrict__ src,
                                ushort4* __restrict__ dst, int n4) {
    int i = blockIdx.x * 256 + threadIdx.x;
    if (i < n4) {
        float4 v = src[i];
        ushort4 o;
        o.x = f2bf(v.x); o.y = f2bf(v.y); o.z = f2bf(v.z); o.w = f2bf(v.w);
        dst[i] = o;
    }
}

// ---------------- fused gather + FC GEMM + tanh + score ----------------
// Persistent-block cross-tile pipeline:
//   iter i:  convert regs(tile i) -> bf16 LDS buf[p]   (gathers issued iter i-1)
//            BARRIER(lgkm only)
//            MFMA K-loop on buf[p]
//            issue gathers(tile i+1)  [AFTER wfc loads -> no in-order vmcnt drain]
//            issue index loads(tile i+2)
//            tanh/score epilogue      [hides gather latency]
//            BARRIER(lgkm only); score write; p ^= 1
// Slot map: thread owns row r = tid&31, column phase w5 = tid>>5;
// slots j=0..3 -> node[starts], 4..7 -> path[paths], 8..11 -> node[ends].
__global__ __launch_bounds__(256, 3)
void fc_kernel(const int* __restrict__ starts, const int* __restrict__ paths,
               const int* __restrict__ ends,
               const float* __restrict__ node_emb, const float* __restrict__ path_emb,
               const u16* __restrict__ wfc, const float* __restrict__ a_vec,
               u16* __restrict__ h_out, float* __restrict__ scores) {
    __shared__ u16 Ab[2][32 * 392];    // 2 x 25088 B bf16 ping-pong (stride 392 u16)
    __shared__ float scpart[4][32];

    const int tid  = threadIdx.x;
    const int lane = tid & 63;
    const int wave = tid >> 6;
    const int lrow = lane & 15;
    const int quad = lane >> 4;
    const int r    = tid & 31;   // staged row owned by this thread
    const int w5   = tid >> 5;   // float4 column phase 0..7

    // hoisted per-thread attention-vector loads (constant across tiles)
    float av[6];
    #pragma unroll
    for (int j = 0; j < 6; ++j) av[j] = a_vec[(wave * 6 + j) * 16 + lrow];

    const u16* bB = wfc + (wave * 96 + lrow) * 384 + quad * 8;

    int    si, pi, ei;   // indices for NEXT tile's gathers
    float4 dat[12];      // in-flight gathers for NEXT tile

    int t = blockIdx.x;
    // ---- prologue: idx(t) -> gathers(t) -> idx(t+FCG_) ----
    {
        const int m = t * 32 + r;
        si = starts[m]; pi = paths[m]; ei = ends[m];
    }
    {
        const float* nb = node_emb + (long)si * 128 + w5 * 4;
        const float* pb = path_emb + (long)pi * 128 + w5 * 4;
        const float* eb = node_emb + (long)ei * 128 + w5 * 4;
        #pragma unroll
        for (int j = 0; j < 4; ++j) {
            dat[j]     = *(const float4*)(nb + j * 32);
            dat[4 + j] = *(const float4*)(pb + j * 32);
            dat[8 + j] = *(const float4*)(eb + j * 32);
        }
    }
    {
        const int tn = (t + FCG_ < NT_) ? (t + FCG_) : t;   // clamp: uniform, no branch
        const int m = tn * 32 + r;
        si = starts[m]; pi = paths[m]; ei = ends[m];
    }

    int p = 0;
    for (; t < NT_; t += FCG_) {
        u16* dst = Ab[p];

        // ---- A: convert in-flight tile -> bf16 LDS ----
        {
            u16* drow = dst + r * 392 + w5 * 4;
            #pragma unroll
            for (int j = 0; j < 12; ++j) {
                float4 v = dat[j];
                ushort4 o;
                o.x = f2bf(v.x); o.y = f2bf(v.y); o.z = f2bf(v.z); o.w = f2bf(v.w);
                *(ushort4*)(drow + j * 32) = o;
            }
        }
        WG_BARRIER();   // ds_writes visible; vmcnt NOT drained

        // ---- D: MFMA K-loop (wfc from global, L1/L2-hot) ----
        const u16* aB0 = dst + lrow * 392 + quad * 8;
        const u16* aB1 = dst + (16 + lrow) * 392 + quad * 8;
        f32x4 acc[2][6];
        #pragma unroll
        for (int mt = 0; mt < 2; ++mt)
            #pragma unroll
            for (int j = 0; j < 6; ++j) acc[mt][j] = (f32x4){0.f, 0.f, 0.f, 0.f};

        for (int kk = 0; kk < 12; ++kk) {
            bf16x8 a0 = *(const bf16x8*)(aB0 + kk * 32);
            bf16x8 a1 = *(const bf16x8*)(aB1 + kk * 32);
            #pragma unroll
            for (int j = 0; j < 6; ++j) {
                bf16x8 bfr = *(const bf16x8*)(bB + j * (16 * 384) + kk * 32);
                acc[0][j] = __builtin_amdgcn_mfma_f32_16x16x32_bf16(a0, bfr, acc[0][j], 0, 0, 0);
                acc[1][j] = __builtin_amdgcn_mfma_f32_16x16x32_bf16(a1, bfr, acc[1][j], 0, 0, 0);
            }
        }
        __builtin_amdgcn_sched_barrier(0);   // pin: gathers must issue AFTER wfc loads

        // ---- B1: issue next-tile gathers (idx loaded one tile ago) ----
        {
            const float* nb = node_emb + (long)si * 128 + w5 * 4;
            const float* pb = path_emb + (long)pi * 128 + w5 * 4;
            const float* eb = node_emb + (long)ei * 128 + w5 * 4;
            #pragma unroll
            for (int j = 0; j < 4; ++j) {
                dat[j]     = *(const float4*)(nb + j * 32);
                dat[4 + j] = *(const float4*)(pb + j * 32);
                dat[8 + j] = *(const float4*)(eb + j * 32);
            }
        }
        // ---- B2: issue index loads for tile t + 2*FCG_ ----
        {
            int tnn = t + 2 * FCG_;
            tnn = (tnn < NT_) ? tnn : t;    // clamp keeps loads valid & uniform
            const int m = tnn * 32 + r;
            si = starts[m]; pi = paths[m]; ei = ends[m];
        }
        __builtin_amdgcn_sched_barrier(0);   // pin: epilogue stores issue after gathers

        // ---- EP: tanh, h store, score partials (hides gather latency) ----
        const int m0 = t * 32;
        float sc00 = 0.f, sc01 = 0.f, sc02 = 0.f, sc03 = 0.f;
        float sc10 = 0.f, sc11 = 0.f, sc12 = 0.f, sc13 = 0.f;
        #pragma unroll
        for (int j = 0; j < 6; ++j) {
            const int col = (wave * 6 + j) * 16 + lrow;
            const float avj = av[j];
            #pragma unroll
            for (int mt = 0; mt < 2; ++mt) {
                const int mrow = m0 + mt * 16 + quad * 4;
                #pragma unroll
                for (int rr = 0; rr < 4; ++rr) {
                    float pre = acc[mt][j][rr];
                    float e = __expf(2.0f * pre);
                    float hv = 1.0f - 2.0f / (e + 1.0f);
                    h_out[(long)(mrow + rr) * 384 + col] = f2bf(hv);
                    float hs = hv * avj;
                    if (mt == 0) {
                        if      (rr == 0) sc00 += hs; else if (rr == 1) sc01 += hs;
                        else if (rr == 2) sc02 += hs; else              sc03 += hs;
                    } else {
                        if      (rr == 0) sc10 += hs; else if (rr == 1) sc11 += hs;
                        else if (rr == 2) sc12 += hs; else              sc13 += hs;
                    }
                }
            }
        }
        #pragma unroll
        for (int off = 1; off < 16; off <<= 1) {
            sc00 += __shfl_xor(sc00, off); sc01 += __shfl_xor(sc01, off);
            sc02 += __shfl_xor(sc02, off); sc03 += __shfl_xor(sc03, off);
            sc10 += __shfl_xor(sc10, off); sc11 += __shfl_xor(sc11, off);
            sc12 += __shfl_xor(sc12, off); sc13 += __shfl_xor(sc13, off);
        }
        if (lrow == 0) {
            scpart[wave][quad * 4 + 0] = sc00;
            scpart[wave][quad * 4 + 1] = sc01;
            scpart[wave][quad * 4 + 2] = sc02;
            scpart[wave][quad * 4 + 3] = sc03;
            scpart[wave][16 + quad * 4 + 0] = sc10;
            scpart[wave][16 + quad * 4 + 1] = sc11;
            scpart[wave][16 + quad * 4 + 2] = sc12;
            scpart[wave][16 + quad * 4 + 3] = sc13;
        }
        WG_BARRIER();   // scpart visible; gathers still in flight
        if (tid < 32)
            scores[m0 + tid] = scpart[0][tid] + scpart[1][tid] + scpart[2][tid] + scpart[3][tid];
        p ^= 1;
    }
}

// ---------------- softmax over L=200 per batch row (1 wave/block) ----------------
__global__ void softmax_kernel(const float* __restrict__ scores, float* __restrict__ attn) {
    int b = blockIdx.x;
    int t = threadIdx.x;
    const float* s = scores + b * L_;
    float v0 = s[t];
    float v1 = s[t + 64];
    float v2 = s[t + 128];
    float v3 = (t < 8) ? s[t + 192] : -INFINITY;
    float mx = fmaxf(fmaxf(v0, v1), fmaxf(v2, v3));
    #pragma unroll
    for (int off = 1; off < 64; off <<= 1) mx = fmaxf(mx, __shfl_xor(mx, off));
    float e0 = __expf(v0 - mx), e1 = __expf(v1 - mx), e2 = __expf(v2 - mx);
    float e3 = (t < 8) ? __expf(v3 - mx) : 0.f;
    float sum = e0 + e1 + e2 + e3;
    #pragma unroll
    for (int off = 1; off < 64; off <<= 1) sum += __shfl_xor(sum, off);
    float inv = 1.f / sum;
    float* o = attn + b * L_;
    o[t] = e0 * inv; o[t + 64] = e1 * inv; o[t + 128] = e2 * inv;
    if (t < 8) o[t + 192] = e3 * inv;
}

// ---------------- code_vectors = sum_l attn * h (bf16x8 loads, 4-wave L split) ----
__global__ __launch_bounds__(256)
void codevec_kernel(const u16* __restrict__ h, const float* __restrict__ attn,
                    u16* __restrict__ cv) {
    __shared__ float part[4][384];
    const int b = blockIdx.x;
    const int tid = threadIdx.x, lane = tid & 63, wave = tid >> 6;
    float acc[8];
    #pragma unroll
    for (int e = 0; e < 8; ++e) acc[e] = 0.f;
    if (lane < 48) {
        const u16* hp = h + (long)b * (L_ * 384) + lane * 8;
        const float* ap = attn + b * L_;
        #pragma unroll 10
        for (int l = wave; l < L_; l += 4) {
            float w = ap[l];
            bf16x8 v = *(const bf16x8*)(hp + (long)l * 384);
            #pragma unroll
            for (int e = 0; e < 8; ++e) acc[e] += bf2f((u16)v[e]) * w;
        }
        #pragma unroll
        for (int e = 0; e < 8; ++e) part[wave][lane * 8 + e] = acc[e];
    }
    __syncthreads();
    for (int c = tid; c < 384; c += 256) {
        cv[b * 384 + c] = f2bf(part[0][c] + part[1][c] + part[2][c] + part[3][c]);
    }
}

// ---------------- out = cv @ W_out^T + b_out ----------------
__global__ __launch_bounds__(256, 4)
void out_gemm_kernel(const u16* __restrict__ cv, const u16* __restrict__ wout,
                     const float* __restrict__ b_out, float* __restrict__ out) {
    const int tid = threadIdx.x;
    const int lane = tid & 63, wave = tid >> 6;
    const int lrow = lane & 15, quad = lane >> 4;
    const int m0  = blockIdx.x * 64 + wave * 16;
    const int n0b = blockIdx.y * 128;

    f32x4 acc[8];
    #pragma unroll
    for (int i = 0; i < 8; ++i) acc[i] = (f32x4){0.f, 0.f, 0.f, 0.f};

    const u16* aB = cv + (m0 + lrow) * 384 + quad * 8;
    for (int kk = 0; kk < 12; ++kk) {
        bf16x8 af = *(const bf16x8*)(aB + kk * 32);
        #pragma unroll
        for (int t = 0; t < 8; ++t) {
            int n = n0b + t * 16 + lrow;
            n = (n < OUT_) ? n : (OUT_ - 1);
            bf16x8 bfr = *(const bf16x8*)(wout + (long)n * 384 + kk * 32 + quad * 8);
            acc[t] = __builtin_amdgcn_mfma_f32_16x16x32_bf16(af, bfr, acc[t], 0, 0, 0);
        }
    }
    const int mrow = m0 + quad * 4;
    #pragma unroll
    for (int t = 0; t < 8; ++t) {
        int n = n0b + t * 16 + lrow;
        if (n < OUT_) {
            float bias = b_out[n];
            #pragma unroll
            for (int r = 0; r < 4; ++r)
                out[(long)(mrow + r) * OUT_ + n] = acc[t][r] + bias;
        }
    }
}

extern "C" void kernel_launch(void* const* d_in, const int* in_sizes, int n_in,
                              void* d_out, int out_size, void* d_ws, size_t ws_size,
                              hipStream_t stream) {
    const int*   starts   = (const int*)d_in[0];
    const int*   paths    = (const int*)d_in[1];
    const int*   ends     = (const int*)d_in[2];
    const float* node_emb = (const float*)d_in[3];
    const float* path_emb = (const float*)d_in[4];
    const float* W_fc     = (const float*)d_in[5];
    const float* a_vec    = (const float*)d_in[6];
    const float* W_out    = (const float*)d_in[7];
    const float* b_out    = (const float*)d_in[8];
    float* out = (float*)d_out;

    char* ws = (char*)d_ws;
    u16*   h_bf16 = (u16*)ws;   ws += (size_t)M_ * 384 * 2;
    float* scores = (float*)ws; ws += (size_t)M_ * 4;
    float* attn   = (float*)ws; ws += (size_t)M_ * 4;
    u16*   wfc_b  = (u16*)ws;   ws += (size_t)C_ * K_ * 2;
    u16*   wout_b = (u16*)ws;   ws += (size_t)OUT_ * K_ * 2;
    u16*   cv_b   = (u16*)ws;   ws += (size_t)B_ * C_ * 2;

    cvt_bf16_kernel<<<(C_ * K_ / 4 + 255) / 256, 256, 0, stream>>>(
        (const float4*)W_fc, (ushort4*)wfc_b, C_ * K_ / 4);
    cvt_bf16_kernel<<<(OUT_ * K_ / 4 + 255) / 256, 256, 0, stream>>>(
        (const float4*)W_out, (ushort4*)wout_b, OUT_ * K_ / 4);
    fc_kernel<<<FCG_, 256, 0, stream>>>(
        starts, paths, ends, node_emb, path_emb, wfc_b, a_vec, h_bf16, scores);
    softmax_kernel<<<B_, 64, 0, stream>>>(scores, attn);
    codevec_kernel<<<B_, 256, 0, stream>>>(h_bf16, attn, cv_b);
    out_gemm_kernel<<<dim3(16, 79), 256, 0, stream>>>(cv_b, wout_b, b_out, out);
}